// Round 4
// baseline (262.596 us; speedup 1.0000x reference)
//
#include <hip/hip_runtime.h>

#define BATCH 16
#define CH    512
#define NSP   1024
#define HIDD  2048

typedef __bf16 bf16x8 __attribute__((ext_vector_type(8)));
typedef float floatx4 __attribute__((ext_vector_type(4)));

__device__ __forceinline__ float bf2f(unsigned short u) {
    union { unsigned int i; float f; } v; v.i = ((unsigned int)u) << 16; return v.f;
}
__device__ __forceinline__ unsigned short f2bf(float f) {
    union { float f; unsigned int i; } v; v.f = f;
    unsigned int i = v.i;
    return (unsigned short)((i + 0x7FFFu + ((i >> 16) & 1u)) >> 16);
}

// async global->LDS, 16B per lane; LDS dst is wave-uniform base + lane*16
__device__ __forceinline__ void gload16(const void* g, void* l) {
    __builtin_amdgcn_global_load_lds(
        (__attribute__((address_space(1))) unsigned int*)(g),
        (__attribute__((address_space(3))) unsigned int*)(l),
        16, 0, 0);
}
#define MEMFENCE asm volatile("" ::: "memory")

// ---------------------------------------------------------------------------
// C = A (MxK, rm) * B^T (Bm NxK rm). 128x128 tile, BK=32, 4 waves,
// 4x4 mfma 16x16x32. r7-verified fine-vmcnt K-loop: DEPTH+1 LDS buffers,
// distance-DEPTH prefetch, 4 gload16/wave/iter, loop barrier =
//   s_waitcnt vmcnt(4*(DEPTH-1)); s_barrier
//
// MAP: 1 PV: XCD owns 2 batches (8x4 tiles);
//      4 scores: TRIANGULAR (S symmetric), 576 blocks, mirrored epilogue.
// EPI: 5 expP (no-max exp) + chunk sums, MAP4 mirror;
//      6 PV: multiply by 1/rowsum computed in-kernel from aux=Ps.
// Stores ni-inner (line-contiguous) -- r10 verified zero WRITE inflation.
// ---------------------------------------------------------------------------
template<int EPI, int MAP, int DEPTH>
__global__ __launch_bounds__(256, (DEPTH == 2) ? 3 : 2)
void gemm_bt(const unsigned short* __restrict__ A,
             const unsigned short* __restrict__ Bm,
             void* __restrict__ Cout,
             int Nn, int K,
             long sAb, long sBb, long sCb,
             const float* __restrict__ bias, float scale,
             const float* __restrict__ resid,
             float* __restrict__ aux)
{
    constexpr int NBUF = DEPTH + 1;
    __shared__ unsigned short sA[NBUF][128 * 32];
    __shared__ unsigned short sB[NBUF][128 * 32];
    __shared__ float sInv[128];

    const int tid  = threadIdx.x;
    const int lane = tid & 63;
    const int w    = tid >> 6;
    const int quad = lane >> 4;
    const int l15  = lane & 15;
    const int mw   = (w >> 1) * 64;
    const int nw   = (w & 1) * 64;

    const int F = blockIdx.x;
    int m0, n0, b;
    if constexpr (MAP == 1) {        // 512 blocks: 2 batches/XCD, 8x4 tiles
        const int xcd = F & 7, s = F >> 3;
        b = xcd + ((s >> 5) << 3);
        const int j = s & 31; m0 = (j >> 2) << 7; n0 = (j & 3) << 7;
    } else if constexpr (MAP == 3) { // 512 blocks: 16 n-tiles/XCD x 4 m
        const int xcd = F & 7, s = F >> 3;
        b = 0; m0 = (s & 3) << 7; n0 = ((xcd << 4) + (s >> 2)) << 7;
    } else {                         // MAP 4: 576 blocks, triangular scores
        const int xcd = F & 7; int s = F >> 3;   // s in [0,72)
        b = xcd + ((s >= 36) ? 8 : 0);
        if (s >= 36) s -= 36;
        int tm = 0;
        while (s >= 8 - tm) { s -= 8 - tm; tm++; }
        m0 = tm << 7; n0 = (tm + s) << 7;
    }

    // PV: compute 1/rowsum for this block's 128 rows (before staging!)
    if constexpr (EPI == 6) {
        if (tid < 128) {
            const float* p = aux + (size_t)b * NSP * 16
                           + (size_t)(m0 + tid) * 16;
            float s = 0.f;
#pragma unroll
            for (int k = 0; k < 16; k++) s += p[k];
            sInv[tid] = 1.0f / s;
        }
        MEMFENCE;
    }

    A  += (size_t)b * sAb;
    Bm += (size_t)b * sBb;

    const int srow = lane >> 2;
    const int sg   = (lane & 3) ^ ((lane >> 3) & 3);
    const unsigned short* pA = A  + (size_t)(m0 + w * 32 + srow) * K + sg * 8;
    const unsigned short* pB = Bm + (size_t)(n0 + w * 32 + srow) * K + sg * 8;
    const size_t rowskip16 = (size_t)16 * K;
    const int woff = w * 1024;
    const int rslot = ((l15 >> 1) & 3);

    floatx4 acc[4][4];
#pragma unroll
    for (int i = 0; i < 4; i++)
#pragma unroll
        for (int j = 0; j < 4; j++) acc[i][j] = (floatx4){0.f, 0.f, 0.f, 0.f};

    const int nIter = K >> 5;
    const int kLast = K - 32;

#pragma unroll
    for (int d = 0; d < DEPTH; ++d) {
        unsigned short* dA = &sA[d][0] + woff;
        unsigned short* dB = &sB[d][0] + woff;
        gload16(pA + d * 32,             dA);
        gload16(pA + d * 32 + rowskip16, dA + 512);
        gload16(pB + d * 32,             dB);
        gload16(pB + d * 32 + rowskip16, dB + 512);
        MEMFENCE;
    }

    int bcur = 0, bpf = DEPTH;
    for (int it = 0; it < nIter; ++it) {
        if constexpr (DEPTH == 2)
            asm volatile("s_waitcnt vmcnt(4)\n\ts_barrier" ::: "memory");
        else
            asm volatile("s_waitcnt vmcnt(8)\n\ts_barrier" ::: "memory");

        const int kpf = (it + DEPTH) * 32 <= kLast ? (it + DEPTH) * 32 : kLast;
        unsigned short* dA = &sA[0][0] + bpf * 4096 + woff;
        unsigned short* dB = &sB[0][0] + bpf * 4096 + woff;
        gload16(pA + kpf,             dA);
        gload16(pA + kpf + rowskip16, dA + 512);
        gload16(pB + kpf,             dB);
        gload16(pB + kpf + rowskip16, dB + 512);
        MEMFENCE;

        const unsigned short* bufA = &sA[0][0] + bcur * 4096;
        const unsigned short* bufB = &sB[0][0] + bcur * 4096;
        bf16x8 af[4], bfr[4];
#pragma unroll
        for (int mi = 0; mi < 4; mi++)
            af[mi] = *(const bf16x8*)(bufA + (mw + mi * 16 + l15) * 32
                                      + (quad ^ rslot) * 8);
#pragma unroll
        for (int ni = 0; ni < 4; ni++)
            bfr[ni] = *(const bf16x8*)(bufB + (nw + ni * 16 + l15) * 32
                                       + (quad ^ rslot) * 8);
#pragma unroll
        for (int mi = 0; mi < 4; mi++)
#pragma unroll
            for (int ni = 0; ni < 4; ni++)
                acc[mi][ni] = __builtin_amdgcn_mfma_f32_16x16x32_bf16(
                    af[mi], bfr[ni], acc[mi][ni], 0, 0, 0);

        bcur = bcur == NBUF - 1 ? 0 : bcur + 1;
        bpf  = bpf  == NBUF - 1 ? 0 : bpf  + 1;
    }
    asm volatile("s_waitcnt vmcnt(0)" ::: "memory");

    // epilogues: D row = quad*4 + reg, col = lane&15  (m89/m91-verified)
    if constexpr (EPI == 4) {
        float* Of = (float*)Cout;
#pragma unroll
        for (int mi = 0; mi < 4; mi++) {
#pragma unroll
            for (int r = 0; r < 4; r++) {
                const int c = m0 + mw + mi * 16 + quad * 4 + r;
                const float bv = bias[c];
#pragma unroll
                for (int ni = 0; ni < 4; ni++) {
                    const int j  = n0 + nw + ni * 16 + l15;
                    const int bb = j >> 10, ns = j & 1023;
                    const size_t a = (size_t)bb * CH * NSP + (size_t)c * NSP + ns;
                    Of[a] = acc[mi][ni][r] + bv + resid[a];
                }
            }
        }
    } else if constexpr (EPI == 5) {
#pragma unroll
        for (int mi = 0; mi < 4; mi++)
#pragma unroll
            for (int ni = 0; ni < 4; ni++)
#pragma unroll
                for (int r = 0; r < 4; r++)
                    acc[mi][ni][r] = __expf(acc[mi][ni][r] * scale);
        {
            const int chunk = (n0 + nw) >> 6;
            float* ps = aux + (size_t)b * NSP * 16;
#pragma unroll
            for (int mi = 0; mi < 4; mi++) {
#pragma unroll
                for (int r = 0; r < 4; r++) {
                    float s = acc[mi][0][r] + acc[mi][1][r]
                            + acc[mi][2][r] + acc[mi][3][r];
                    s += __shfl_xor(s, 1);
                    s += __shfl_xor(s, 2);
                    s += __shfl_xor(s, 4);
                    s += __shfl_xor(s, 8);
                    if (l15 == 0)
                        ps[(size_t)(m0 + mw + mi * 16 + quad * 4 + r) * 16
                           + chunk] = s;
                }
            }
        }
        unsigned short* Cb = (unsigned short*)Cout + (size_t)b * sCb;
#pragma unroll
        for (int mi = 0; mi < 4; mi++) {
#pragma unroll
            for (int r = 0; r < 4; r++) {
                const size_t rowoff =
                    (size_t)(m0 + mw + mi * 16 + quad * 4 + r) * Nn;
#pragma unroll
                for (int ni = 0; ni < 4; ni++)
                    Cb[rowoff + n0 + nw + ni * 16 + l15] =
                        f2bf(acc[mi][ni][r]);
            }
        }
        if constexpr (MAP == 4) {
            if (m0 != n0) {
                const int chunkt = (m0 + mw) >> 6;
                float* ps = aux + (size_t)b * NSP * 16;
#pragma unroll
                for (int ni = 0; ni < 4; ni++) {
                    float s = 0.f;
#pragma unroll
                    for (int mi = 0; mi < 4; mi++)
#pragma unroll
                        for (int r = 0; r < 4; r++) s += acc[mi][ni][r];
                    s += __shfl_xor(s, 16);
                    s += __shfl_xor(s, 32);
                    if (quad == 0)
                        ps[(size_t)(n0 + nw + ni * 16 + l15) * 16 + chunkt] = s;
                }
#pragma unroll
                for (int ni = 0; ni < 4; ni++) {
                    const size_t rowoff =
                        (size_t)(n0 + nw + ni * 16 + l15) * Nn;
#pragma unroll
                    for (int mi = 0; mi < 4; mi++) {
                        ushort4 v;
                        v.x = f2bf(acc[mi][ni][0]);
                        v.y = f2bf(acc[mi][ni][1]);
                        v.z = f2bf(acc[mi][ni][2]);
                        v.w = f2bf(acc[mi][ni][3]);
                        *(ushort4*)(Cb + rowoff + m0 + mw + mi * 16 + quad * 4)
                            = v;
                    }
                }
            }
        }
    } else {  // EPI == 6: PV, multiply by sInv[row]
        __syncthreads();   // publish sInv ds_writes to all waves
        unsigned short* Cb = (unsigned short*)Cout + (size_t)b * sCb;
#pragma unroll
        for (int mi = 0; mi < 4; mi++) {
#pragma unroll
            for (int r = 0; r < 4; r++) {
                const int lrow = mw + mi * 16 + quad * 4 + r;
                const float iv = sInv[lrow];
                const size_t rowoff = (size_t)(m0 + lrow) * Nn;
#pragma unroll
                for (int ni = 0; ni < 4; ni++)
                    Cb[rowoff + n0 + nw + ni * 16 + l15] =
                        f2bf(acc[mi][ni][r] * iv);
            }
        }
    }
}

// ---------------------------------------------------------------------------
// r15: final GEMM out = (W2 * H^T)^T-store + b2 + x, 128x128 tile,
// 2-K-TILES-PER-BODY loop. 4 bufs BK=32, one vmcnt(8) wait per 2 tiles,
// mid-barrier refill of just-freed buffers. ~1kcy/sync-round cost model
// calibrated by r15's win (65.5 -> <64, total -14us).
// MAP: XCD owns 16 n-tiles x 4 m (r13's MAP3).
// ---------------------------------------------------------------------------
__global__ __launch_bounds__(256, 2)
void gemm_final_u2(const unsigned short* __restrict__ A,   // W2b [512][2048]
                   const unsigned short* __restrict__ Bm,  // Hb [16384][2048]
                   float* __restrict__ Of,                 // out fp32
                   const float* __restrict__ bias,         // b2 [512]
                   const float* __restrict__ resid)        // x  fp32
{
    const int K = HIDD;                        // 2048, 64 K-tiles, 32 bodies
    __shared__ unsigned short sA[4][128 * 32]; // 4 x 8 KB
    __shared__ unsigned short sB[4][128 * 32]; // 4 x 8 KB  -> 64 KB total

    const int tid  = threadIdx.x;
    const int lane = tid & 63;
    const int w    = tid >> 6;
    const int quad = lane >> 4;
    const int l15  = lane & 15;
    const int mw   = (w >> 1) * 64;
    const int nw   = (w & 1) * 64;

    const int F = blockIdx.x;              // 512 blocks
    const int xcd = F & 7, s = F >> 3;     // MAP3: 16 n-tiles/XCD x 4 m
    const int m0 = (s & 3) << 7;
    const int n0 = ((xcd << 4) + (s >> 2)) << 7;

    const int srow = lane >> 2;
    const int sg   = (lane & 3) ^ ((lane >> 3) & 3);
    const unsigned short* pA = A  + (size_t)(m0 + w * 32 + srow) * K + sg * 8;
    const unsigned short* pB = Bm + (size_t)(n0 + w * 32 + srow) * K + sg * 8;
    const size_t rowskip16 = (size_t)16 * K;
    const int woff = w * 1024;
    const int rslot = ((l15 >> 1) & 3);

    floatx4 acc[4][4];
#pragma unroll
    for (int i = 0; i < 4; i++)
#pragma unroll
        for (int j = 0; j < 4; j++) acc[i][j] = (floatx4){0.f, 0.f, 0.f, 0.f};

    const int kLast = K - 32;

    // prologue: stage K-tiles 0..3 into bufs 0..3 (16 loads/wave)
#pragma unroll
    for (int d = 0; d < 4; ++d) {
        unsigned short* dA = &sA[d][0] + woff;
        unsigned short* dB = &sB[d][0] + woff;
        gload16(pA + d * 32,             dA);
        gload16(pA + d * 32 + rowskip16, dA + 512);
        gload16(pB + d * 32,             dB);
        gload16(pB + d * 32 + rowskip16, dB + 512);
        MEMFENCE;
    }

    const int nBody = K >> 6;   // 32 bodies, 2 K-tiles each
    for (int i = 0; i < nBody; ++i) {
        // retire the 8 loads of K-tiles {2i, 2i+1}; keep {2i+2,2i+3} in flight
        asm volatile("s_waitcnt vmcnt(8)\n\ts_barrier" ::: "memory");

#pragma unroll
        for (int t = 0; t < 2; ++t) {
            const int buf = (2 * i + t) & 3;
            const unsigned short* bufA = &sA[buf][0];
            const unsigned short* bufB = &sB[buf][0];
            bf16x8 af[4], bfr[4];
#pragma unroll
            for (int mi = 0; mi < 4; mi++)
                af[mi] = *(const bf16x8*)(bufA + (mw + mi * 16 + l15) * 32
                                          + (quad ^ rslot) * 8);
#pragma unroll
            for (int ni = 0; ni < 4; ni++)
                bfr[ni] = *(const bf16x8*)(bufB + (nw + ni * 16 + l15) * 32
                                           + (quad ^ rslot) * 8);
#pragma unroll
            for (int mi = 0; mi < 4; mi++)
#pragma unroll
                for (int ni = 0; ni < 4; ni++)
                    acc[mi][ni] = __builtin_amdgcn_mfma_f32_16x16x32_bf16(
                        af[mi], bfr[ni], acc[mi][ni], 0, 0, 0);
        }

        // all waves done reading bufs {2i,2i+1}; refill them with {2i+4,2i+5}
        __builtin_amdgcn_s_barrier();
#pragma unroll
        for (int t = 0; t < 2; ++t) {
            const int kt = 2 * i + 4 + t;
            const int kpf = (kt * 32 <= kLast) ? kt * 32 : kLast;  // clamp tail
            const int buf = kt & 3;            // == (2i+t)&3, just freed
            unsigned short* dA = &sA[buf][0] + woff;
            unsigned short* dB = &sB[buf][0] + woff;
            gload16(pA + kpf,             dA);
            gload16(pA + kpf + rowskip16, dA + 512);
            gload16(pB + kpf,             dB);
            gload16(pB + kpf + rowskip16, dB + 512);
            MEMFENCE;
        }
    }
    asm volatile("s_waitcnt vmcnt(0)" ::: "memory");

    // epilogue: transposed fp32 store + bias + resid (line-contiguous in ns)
#pragma unroll
    for (int mi = 0; mi < 4; mi++) {
#pragma unroll
        for (int r = 0; r < 4; r++) {
            const int c = m0 + mw + mi * 16 + quad * 4 + r;
            const float bv = bias[c];
#pragma unroll
            for (int ni = 0; ni < 4; ni++) {
                const int j  = n0 + nw + ni * 16 + l15;
                const int bb = j >> 10, ns = j & 1023;
                const size_t a = (size_t)bb * CH * NSP + (size_t)c * NSP + ns;
                Of[a] = acc[mi][ni][r] + bv + resid[a];
            }
        }
    }
}

// ---------------------------------------------------------------------------
// FFN1 wide tile: Hb = relu(O * W1^T + b1). 128m x 256n block tile, BK=32,
// 4 waves, wave tile 64x128 (acc 4x8 -> 32 MFMA/iter).
//
// r16 (this round): 3 blocks/CU via NBUF=2 (48KB LDS, launch_bounds(256,3)).
// r13's L2 fix landed (FETCH 67.6->24.7MB) but dur stayed ~64us: limiter is
// the latency/sync stall at 2 blocks/CU (72KB LDS). scores/PV at 3 blocks/CU
// run faster on comparable FLOPs; m97's 37%-MfmaUtil regime = ~3 blocks/CU.
// Structure = r15's proven double-barrier body: wait vmcnt(6)+barrier ->
// compute buf[it&1] -> barrier -> refill just-freed buffer with tile it+2
// (clamp-staged unconditionally so vmcnt stays uniform through the tail).
// Load flight time >= 1 full iteration >> 900cy HBM latency.
// MAP: XCD-chunked (16 m-tiles x 8 n per XCD, n-fastest inside) -- r13.
// ---------------------------------------------------------------------------
__global__ __launch_bounds__(256, 3)
void ffn1_wide(const unsigned short* __restrict__ A,   // O  [16384][512]
               const unsigned short* __restrict__ Bm,  // W1 [2048][512]
               unsigned short* __restrict__ Cout,      // Hb [16384][2048]
               const float* __restrict__ bias)
{
    const int K = CH, Nn = HIDD;
    __shared__ unsigned short sA[2][128 * 32];   // 2 x 8 KB
    __shared__ unsigned short sB[2][256 * 32];   // 2 x 16 KB  -> 48 KB total

    const int tid  = threadIdx.x;
    const int lane = tid & 63;
    const int w    = tid >> 6;
    const int quad = lane >> 4;
    const int l15  = lane & 15;
    const int mw   = (w >> 1) * 64;
    const int nw   = (w & 1) * 128;

    const int F = blockIdx.x;              // 1024 blocks
    const int xcd = F & 7, s = F >> 3;     // XCD-chunked: 16 m-tiles x 8 n
    const int m0 = ((xcd << 4) + (s >> 3)) << 7;   // n-fastest within XCD
    const int n0 = (s & 7) << 8;

    const int srow = lane >> 2;
    const int sg   = (lane & 3) ^ ((lane >> 3) & 3);
    const unsigned short* pA = A  + (size_t)(m0 + w * 32 + srow) * K + sg * 8;
    const unsigned short* pB = Bm + (size_t)(n0 + w * 64 + srow) * K + sg * 8;
    const size_t rowskip16 = (size_t)16 * K;
    const int woffA = w * 1024;            // 32 rows
    const int woffB = w * 2048;            // 64 rows
    const int rslot = ((l15 >> 1) & 3);

    floatx4 acc[4][8];
#pragma unroll
    for (int i = 0; i < 4; i++)
#pragma unroll
        for (int j = 0; j < 8; j++) acc[i][j] = (floatx4){0.f, 0.f, 0.f, 0.f};

    const int nIter = K >> 5;   // 16
    const int kLast = K - 32;

    // prologue: tiles 0,1 into bufs 0,1 (12 ops/wave outstanding)
#pragma unroll
    for (int d = 0; d < 2; ++d) {
        unsigned short* dA = &sA[d][0] + woffA;
        unsigned short* dB = &sB[d][0] + woffB;
        gload16(pA + d * 32,                 dA);
        gload16(pA + d * 32 +     rowskip16, dA + 512);
        gload16(pB + d * 32,                 dB);
        gload16(pB + d * 32 +     rowskip16, dB + 512);
        gload16(pB + d * 32 + 2 * rowskip16, dB + 1024);
        gload16(pB + d * 32 + 3 * rowskip16, dB + 1536);
        MEMFENCE;
    }

    for (int it = 0; it < nIter; ++it) {
        // retire tile it's 6 loads; tile it+1's 6 stay in flight
        asm volatile("s_waitcnt vmcnt(6)\n\ts_barrier" ::: "memory");

        const int cur = it & 1;
        const unsigned short* bufA = &sA[cur][0];
        const unsigned short* bufB = &sB[cur][0];
        bf16x8 af[4], bfr[8];
#pragma unroll
        for (int mi = 0; mi < 4; mi++)
            af[mi] = *(const bf16x8*)(bufA + (mw + mi * 16 + l15) * 32
                                      + (quad ^ rslot) * 8);
#pragma unroll
        for (int ni = 0; ni < 8; ni++)
            bfr[ni] = *(const bf16x8*)(bufB + (nw + ni * 16 + l15) * 32
                                       + (quad ^ rslot) * 8);
#pragma unroll
        for (int mi = 0; mi < 4; mi++)
#pragma unroll
            for (int ni = 0; ni < 8; ni++)
                acc[mi][ni] = __builtin_amdgcn_mfma_f32_16x16x32_bf16(
                    af[mi], bfr[ni], acc[mi][ni], 0, 0, 0);

        // all waves done reading buf[cur]; refill it with tile it+2
        // (clamped at the tail so per-wave vmcnt stays uniform)
        __builtin_amdgcn_s_barrier();
        const int kpf = (it + 2) * 32 <= kLast ? (it + 2) * 32 : kLast;
        unsigned short* dA = &sA[cur][0] + woffA;
        unsigned short* dB = &sB[cur][0] + woffB;
        gload16(pA + kpf,                 dA);
        gload16(pA + kpf +     rowskip16, dA + 512);
        gload16(pB + kpf,                 dB);
        gload16(pB + kpf +     rowskip16, dB + 512);
        gload16(pB + kpf + 2 * rowskip16, dB + 1024);
        gload16(pB + kpf + 3 * rowskip16, dB + 1536);
        MEMFENCE;
    }
    asm volatile("s_waitcnt vmcnt(0)" ::: "memory");

    // epilogue: +bias, relu -> bf16; ni-inner (line-contiguous)
    float bv[8];
#pragma unroll
    for (int ni = 0; ni < 8; ni++) bv[ni] = bias[n0 + nw + ni * 16 + l15];
#pragma unroll
    for (int mi = 0; mi < 4; mi++) {
#pragma unroll
        for (int r = 0; r < 4; r++) {
            const size_t rowoff =
                (size_t)(m0 + mw + mi * 16 + quad * 4 + r) * Nn;
#pragma unroll
            for (int ni = 0; ni < 8; ni++)
                Cout[rowoff + n0 + nw + ni * 16 + l15] =
                    f2bf(fmaxf(acc[mi][ni][r] + bv[ni], 0.f));
        }
    }
}

// merged prep: z<16 -> pack x (bf16 X + X^T); z>=16 -> cast w1,w2 to bf16
__global__ __launch_bounds__(256)
void prep_kernel(const float* __restrict__ x,
                 unsigned short* __restrict__ Xbf,
                 unsigned short* __restrict__ XT,
                 const float* __restrict__ w1,
                 unsigned short* __restrict__ W1b,
                 const float* __restrict__ w2,
                 unsigned short* __restrict__ W2b)
{
    const int tx = threadIdx.x, ty = threadIdx.y;
    const int z = blockIdx.z;
    if (z < 16) {
        __shared__ float tile[32][33];
        const int n0 = blockIdx.x * 32, c0 = blockIdx.y * 32, b = z;
        const size_t base = (size_t)b * CH * NSP;
#pragma unroll
        for (int i = ty; i < 32; i += 8) {
            float v = x[base + (size_t)(c0 + i) * NSP + n0 + tx];
            tile[i][tx] = v;
            Xbf[base + (size_t)(c0 + i) * NSP + n0 + tx] = f2bf(v);
        }
        __syncthreads();
        const size_t tbase = (size_t)b * NSP * CH;
#pragma unroll
        for (int i = ty; i < 32; i += 8)
            XT[tbase + (size_t)(n0 + i) * CH + c0 + tx] = f2bf(tile[tx][i]);
    } else {
        const int tid = ty * 32 + tx;
        const int blk = (z - 16) * 512 + blockIdx.y * 32 + blockIdx.x;
        const int i = blk * 256 + tid;                 // [0, 2*HIDD*CH)
        if (i < HIDD * CH) W1b[i] = f2bf(w1[i]);
        else               W2b[i - HIDD * CH] = f2bf(w2[i - HIDD * CH]);
    }
}

extern "C" void kernel_launch(void* const* d_in, const int* in_sizes, int n_in,
                              void* d_out, int out_size, void* d_ws, size_t ws_size,
                              hipStream_t stream)
{
    const float* x  = (const float*)d_in[0];
    const float* w1 = (const float*)d_in[1];
    const float* b1 = (const float*)d_in[2];
    const float* w2 = (const float*)d_in[3];
    const float* b2 = (const float*)d_in[4];
    float* out = (float*)d_out;

    char* ws = (char*)d_ws;
    unsigned short* Xbf = (unsigned short*)ws; ws += (size_t)BATCH * CH * NSP * 2;   // 16 MB
    unsigned short* XT  = (unsigned short*)ws; ws += (size_t)BATCH * NSP * CH * 2;   // 16 MB
    unsigned short* W1b = (unsigned short*)ws; ws += (size_t)HIDD * CH * 2;          //  2 MB
    unsigned short* W2b = (unsigned short*)ws; ws += (size_t)CH * HIDD * 2;          //  2 MB
    unsigned short* P   = (unsigned short*)ws; ws += (size_t)BATCH * NSP * NSP * 2;  // 32 MB
    unsigned short* O   = (unsigned short*)ws; ws += (size_t)BATCH * NSP * CH * 2;   // 16 MB
    unsigned short* Hb  = (unsigned short*)ws; ws += (size_t)BATCH * NSP * HIDD * 2; // 64 MB
    float*          Ps  = (float*)ws;          ws += (size_t)BATCH * NSP * 16 * 4;   //  1 MB

    const dim3 blk(256);

    // pack x (X, X^T) + cast weights, one launch
    prep_kernel<<<dim3(32, 16, 32), dim3(32, 8), 0, stream>>>(
        x, Xbf, XT, w1, W1b, w2, W2b);

    // expP = exp(scale * XT * XT^T) -> P (bf16) + chunk sums -> Ps
    // triangular: 36 tiles/batch, off-diag mirrored in epilogue
    gemm_bt<5, 4, 2><<<dim3(576), blk, 0, stream>>>(
        XT, XT, P, NSP, CH,
        (long)NSP * CH, (long)NSP * CH, (long)NSP * NSP, nullptr,
        0.04419417382415922f, nullptr, Ps);

    // O = (expP * X^T) * (1/rowsum)  — rowsum folded into PV prologue
    gemm_bt<6, 1, 2><<<dim3(512), blk, 0, stream>>>(
        P, Xbf, O, CH, NSP,
        (long)NSP * NSP, (long)CH * NSP, (long)NSP * CH, nullptr, 1.f,
        nullptr, Ps);

    // H = relu(O * W1^T + b1)  — r16: NBUF=2, 48KB LDS, 3 blocks/CU
    ffn1_wide<<<dim3(1024), blk, 0, stream>>>(O, W1b, Hb, b1);

    // out = (W2 * H^T)[c][b*n] + b2[c] + x  — r15: 2-K-tiles-per-body loop
    gemm_final_u2<<<dim3(512), blk, 0, stream>>>(
        W2b, Hb, out, b2, x);
}

// Round 5
// 237.354 us; speedup vs baseline: 1.1063x; 1.1063x over previous
//
#include <hip/hip_runtime.h>

#define BATCH 16
#define CH    512
#define NSP   1024
#define HIDD  2048

typedef __bf16 bf16x8 __attribute__((ext_vector_type(8)));
typedef float floatx4 __attribute__((ext_vector_type(4)));

__device__ __forceinline__ float bf2f(unsigned short u) {
    union { unsigned int i; float f; } v; v.i = ((unsigned int)u) << 16; return v.f;
}
__device__ __forceinline__ unsigned short f2bf(float f) {
    union { float f; unsigned int i; } v; v.f = f;
    unsigned int i = v.i;
    return (unsigned short)((i + 0x7FFFu + ((i >> 16) & 1u)) >> 16);
}

// async global->LDS, 16B per lane; LDS dst is wave-uniform base + lane*16
__device__ __forceinline__ void gload16(const void* g, void* l) {
    __builtin_amdgcn_global_load_lds(
        (__attribute__((address_space(1))) unsigned int*)(g),
        (__attribute__((address_space(3))) unsigned int*)(l),
        16, 0, 0);
}
#define MEMFENCE asm volatile("" ::: "memory")
#define SBARRIER asm volatile("s_barrier" ::: "memory")

// ---------------------------------------------------------------------------
// C = A (MxK, rm) * B^T (Bm NxK rm). 128x128 tile, BK=32, 4 waves,
// 4x4 mfma 16x16x32. r7-verified fine-vmcnt K-loop: DEPTH+1 LDS buffers,
// distance-DEPTH prefetch, 4 gload16/wave/iter, loop barrier =
//   s_waitcnt vmcnt(4*(DEPTH-1)); s_barrier
//
// MAP: 1 PV: XCD owns 2 batches (8x4 tiles);
//      4 scores: TRIANGULAR (S symmetric), 576 blocks, mirrored epilogue.
// EPI: 5 expP (no-max exp) + chunk sums, MAP4 mirror;
//      6 PV: multiply by 1/rowsum computed in-kernel from aux=Ps.
// Stores ni-inner (line-contiguous) -- r10 verified zero WRITE inflation.
// ---------------------------------------------------------------------------
template<int EPI, int MAP, int DEPTH>
__global__ __launch_bounds__(256, (DEPTH == 2) ? 3 : 2)
void gemm_bt(const unsigned short* __restrict__ A,
             const unsigned short* __restrict__ Bm,
             void* __restrict__ Cout,
             int Nn, int K,
             long sAb, long sBb, long sCb,
             const float* __restrict__ bias, float scale,
             const float* __restrict__ resid,
             float* __restrict__ aux)
{
    constexpr int NBUF = DEPTH + 1;
    __shared__ unsigned short sA[NBUF][128 * 32];
    __shared__ unsigned short sB[NBUF][128 * 32];
    __shared__ float sInv[128];

    const int tid  = threadIdx.x;
    const int lane = tid & 63;
    const int w    = tid >> 6;
    const int quad = lane >> 4;
    const int l15  = lane & 15;
    const int mw   = (w >> 1) * 64;
    const int nw   = (w & 1) * 64;

    const int F = blockIdx.x;
    int m0, n0, b;
    if constexpr (MAP == 1) {        // 512 blocks: 2 batches/XCD, 8x4 tiles
        const int xcd = F & 7, s = F >> 3;
        b = xcd + ((s >> 5) << 3);
        const int j = s & 31; m0 = (j >> 2) << 7; n0 = (j & 3) << 7;
    } else if constexpr (MAP == 3) { // 512 blocks: 16 n-tiles/XCD x 4 m
        const int xcd = F & 7, s = F >> 3;
        b = 0; m0 = (s & 3) << 7; n0 = ((xcd << 4) + (s >> 2)) << 7;
    } else {                         // MAP 4: 576 blocks, triangular scores
        const int xcd = F & 7; int s = F >> 3;   // s in [0,72)
        b = xcd + ((s >= 36) ? 8 : 0);
        if (s >= 36) s -= 36;
        int tm = 0;
        while (s >= 8 - tm) { s -= 8 - tm; tm++; }
        m0 = tm << 7; n0 = (tm + s) << 7;
    }

    // PV: compute 1/rowsum for this block's 128 rows (before staging!)
    if constexpr (EPI == 6) {
        if (tid < 128) {
            const float* p = aux + (size_t)b * NSP * 16
                           + (size_t)(m0 + tid) * 16;
            float s = 0.f;
#pragma unroll
            for (int k = 0; k < 16; k++) s += p[k];
            sInv[tid] = 1.0f / s;
        }
        MEMFENCE;
    }

    A  += (size_t)b * sAb;
    Bm += (size_t)b * sBb;

    const int srow = lane >> 2;
    const int sg   = (lane & 3) ^ ((lane >> 3) & 3);
    const unsigned short* pA = A  + (size_t)(m0 + w * 32 + srow) * K + sg * 8;
    const unsigned short* pB = Bm + (size_t)(n0 + w * 32 + srow) * K + sg * 8;
    const size_t rowskip16 = (size_t)16 * K;
    const int woff = w * 1024;
    const int rslot = ((l15 >> 1) & 3);

    floatx4 acc[4][4];
#pragma unroll
    for (int i = 0; i < 4; i++)
#pragma unroll
        for (int j = 0; j < 4; j++) acc[i][j] = (floatx4){0.f, 0.f, 0.f, 0.f};

    const int nIter = K >> 5;
    const int kLast = K - 32;

#pragma unroll
    for (int d = 0; d < DEPTH; ++d) {
        unsigned short* dA = &sA[d][0] + woff;
        unsigned short* dB = &sB[d][0] + woff;
        gload16(pA + d * 32,             dA);
        gload16(pA + d * 32 + rowskip16, dA + 512);
        gload16(pB + d * 32,             dB);
        gload16(pB + d * 32 + rowskip16, dB + 512);
        MEMFENCE;
    }

    int bcur = 0, bpf = DEPTH;
    for (int it = 0; it < nIter; ++it) {
        if constexpr (DEPTH == 2)
            asm volatile("s_waitcnt vmcnt(4)\n\ts_barrier" ::: "memory");
        else
            asm volatile("s_waitcnt vmcnt(8)\n\ts_barrier" ::: "memory");

        const int kpf = (it + DEPTH) * 32 <= kLast ? (it + DEPTH) * 32 : kLast;
        unsigned short* dA = &sA[0][0] + bpf * 4096 + woff;
        unsigned short* dB = &sB[0][0] + bpf * 4096 + woff;
        gload16(pA + kpf,             dA);
        gload16(pA + kpf + rowskip16, dA + 512);
        gload16(pB + kpf,             dB);
        gload16(pB + kpf + rowskip16, dB + 512);
        MEMFENCE;

        const unsigned short* bufA = &sA[0][0] + bcur * 4096;
        const unsigned short* bufB = &sB[0][0] + bcur * 4096;
        bf16x8 af[4], bfr[4];
#pragma unroll
        for (int mi = 0; mi < 4; mi++)
            af[mi] = *(const bf16x8*)(bufA + (mw + mi * 16 + l15) * 32
                                      + (quad ^ rslot) * 8);
#pragma unroll
        for (int ni = 0; ni < 4; ni++)
            bfr[ni] = *(const bf16x8*)(bufB + (nw + ni * 16 + l15) * 32
                                       + (quad ^ rslot) * 8);
#pragma unroll
        for (int mi = 0; mi < 4; mi++)
#pragma unroll
            for (int ni = 0; ni < 4; ni++)
                acc[mi][ni] = __builtin_amdgcn_mfma_f32_16x16x32_bf16(
                    af[mi], bfr[ni], acc[mi][ni], 0, 0, 0);

        bcur = bcur == NBUF - 1 ? 0 : bcur + 1;
        bpf  = bpf  == NBUF - 1 ? 0 : bpf  + 1;
    }
    asm volatile("s_waitcnt vmcnt(0)" ::: "memory");

    // epilogues: D row = quad*4 + reg, col = lane&15  (m89/m91-verified)
    if constexpr (EPI == 4) {
        float* Of = (float*)Cout;
#pragma unroll
        for (int mi = 0; mi < 4; mi++) {
#pragma unroll
            for (int r = 0; r < 4; r++) {
                const int c = m0 + mw + mi * 16 + quad * 4 + r;
                const float bv = bias[c];
#pragma unroll
                for (int ni = 0; ni < 4; ni++) {
                    const int j  = n0 + nw + ni * 16 + l15;
                    const int bb = j >> 10, ns = j & 1023;
                    const size_t a = (size_t)bb * CH * NSP + (size_t)c * NSP + ns;
                    Of[a] = acc[mi][ni][r] + bv + resid[a];
                }
            }
        }
    } else if constexpr (EPI == 5) {
#pragma unroll
        for (int mi = 0; mi < 4; mi++)
#pragma unroll
            for (int ni = 0; ni < 4; ni++)
#pragma unroll
                for (int r = 0; r < 4; r++)
                    acc[mi][ni][r] = __expf(acc[mi][ni][r] * scale);
        {
            const int chunk = (n0 + nw) >> 6;
            float* ps = aux + (size_t)b * NSP * 16;
#pragma unroll
            for (int mi = 0; mi < 4; mi++) {
#pragma unroll
                for (int r = 0; r < 4; r++) {
                    float s = acc[mi][0][r] + acc[mi][1][r]
                            + acc[mi][2][r] + acc[mi][3][r];
                    s += __shfl_xor(s, 1);
                    s += __shfl_xor(s, 2);
                    s += __shfl_xor(s, 4);
                    s += __shfl_xor(s, 8);
                    if (l15 == 0)
                        ps[(size_t)(m0 + mw + mi * 16 + quad * 4 + r) * 16
                           + chunk] = s;
                }
            }
        }
        unsigned short* Cb = (unsigned short*)Cout + (size_t)b * sCb;
#pragma unroll
        for (int mi = 0; mi < 4; mi++) {
#pragma unroll
            for (int r = 0; r < 4; r++) {
                const size_t rowoff =
                    (size_t)(m0 + mw + mi * 16 + quad * 4 + r) * Nn;
#pragma unroll
                for (int ni = 0; ni < 4; ni++)
                    Cb[rowoff + n0 + nw + ni * 16 + l15] =
                        f2bf(acc[mi][ni][r]);
            }
        }
        if constexpr (MAP == 4) {
            if (m0 != n0) {
                const int chunkt = (m0 + mw) >> 6;
                float* ps = aux + (size_t)b * NSP * 16;
#pragma unroll
                for (int ni = 0; ni < 4; ni++) {
                    float s = 0.f;
#pragma unroll
                    for (int mi = 0; mi < 4; mi++)
#pragma unroll
                        for (int r = 0; r < 4; r++) s += acc[mi][ni][r];
                    s += __shfl_xor(s, 16);
                    s += __shfl_xor(s, 32);
                    if (quad == 0)
                        ps[(size_t)(n0 + nw + ni * 16 + l15) * 16 + chunkt] = s;
                }
#pragma unroll
                for (int ni = 0; ni < 4; ni++) {
                    const size_t rowoff =
                        (size_t)(n0 + nw + ni * 16 + l15) * Nn;
#pragma unroll
                    for (int mi = 0; mi < 4; mi++) {
                        ushort4 v;
                        v.x = f2bf(acc[mi][ni][0]);
                        v.y = f2bf(acc[mi][ni][1]);
                        v.z = f2bf(acc[mi][ni][2]);
                        v.w = f2bf(acc[mi][ni][3]);
                        *(ushort4*)(Cb + rowoff + m0 + mw + mi * 16 + quad * 4)
                            = v;
                    }
                }
            }
        }
    } else {  // EPI == 6: PV, multiply by sInv[row]
        __syncthreads();   // publish sInv ds_writes to all waves
        unsigned short* Cb = (unsigned short*)Cout + (size_t)b * sCb;
#pragma unroll
        for (int mi = 0; mi < 4; mi++) {
#pragma unroll
            for (int r = 0; r < 4; r++) {
                const int lrow = mw + mi * 16 + quad * 4 + r;
                const float iv = sInv[lrow];
                const size_t rowoff = (size_t)(m0 + lrow) * Nn;
#pragma unroll
                for (int ni = 0; ni < 4; ni++)
                    Cb[rowoff + n0 + nw + ni * 16 + l15] =
                        f2bf(acc[mi][ni][r] * iv);
            }
        }
    }
}

// ---------------------------------------------------------------------------
// r15: final GEMM out = (W2 * H^T)^T-store + b2 + x, 128x128 tile,
// 2-K-TILES-PER-BODY loop. 4 bufs BK=32, one vmcnt(8) wait per 2 tiles,
// mid-barrier refill of just-freed buffers. ~1kcy/sync-round cost model
// calibrated by r15's win (65.5 -> <64, total -14us).
// MAP: XCD owns 16 n-tiles x 4 m (r13's MAP3).
// ---------------------------------------------------------------------------
__global__ __launch_bounds__(256, 2)
void gemm_final_u2(const unsigned short* __restrict__ A,   // W2b [512][2048]
                   const unsigned short* __restrict__ Bm,  // Hb [16384][2048]
                   float* __restrict__ Of,                 // out fp32
                   const float* __restrict__ bias,         // b2 [512]
                   const float* __restrict__ resid)        // x  fp32
{
    const int K = HIDD;                        // 2048, 64 K-tiles, 32 bodies
    __shared__ unsigned short sA[4][128 * 32]; // 4 x 8 KB
    __shared__ unsigned short sB[4][128 * 32]; // 4 x 8 KB  -> 64 KB total

    const int tid  = threadIdx.x;
    const int lane = tid & 63;
    const int w    = tid >> 6;
    const int quad = lane >> 4;
    const int l15  = lane & 15;
    const int mw   = (w >> 1) * 64;
    const int nw   = (w & 1) * 64;

    const int F = blockIdx.x;              // 512 blocks
    const int xcd = F & 7, s = F >> 3;     // MAP3: 16 n-tiles/XCD x 4 m
    const int m0 = (s & 3) << 7;
    const int n0 = ((xcd << 4) + (s >> 2)) << 7;

    const int srow = lane >> 2;
    const int sg   = (lane & 3) ^ ((lane >> 3) & 3);
    const unsigned short* pA = A  + (size_t)(m0 + w * 32 + srow) * K + sg * 8;
    const unsigned short* pB = Bm + (size_t)(n0 + w * 32 + srow) * K + sg * 8;
    const size_t rowskip16 = (size_t)16 * K;
    const int woff = w * 1024;
    const int rslot = ((l15 >> 1) & 3);

    floatx4 acc[4][4];
#pragma unroll
    for (int i = 0; i < 4; i++)
#pragma unroll
        for (int j = 0; j < 4; j++) acc[i][j] = (floatx4){0.f, 0.f, 0.f, 0.f};

    const int kLast = K - 32;

    // prologue: stage K-tiles 0..3 into bufs 0..3 (16 loads/wave)
#pragma unroll
    for (int d = 0; d < 4; ++d) {
        unsigned short* dA = &sA[d][0] + woff;
        unsigned short* dB = &sB[d][0] + woff;
        gload16(pA + d * 32,             dA);
        gload16(pA + d * 32 + rowskip16, dA + 512);
        gload16(pB + d * 32,             dB);
        gload16(pB + d * 32 + rowskip16, dB + 512);
        MEMFENCE;
    }

    const int nBody = K >> 6;   // 32 bodies, 2 K-tiles each
    for (int i = 0; i < nBody; ++i) {
        // retire the 8 loads of K-tiles {2i, 2i+1}; keep {2i+2,2i+3} in flight
        asm volatile("s_waitcnt vmcnt(8)\n\ts_barrier" ::: "memory");

#pragma unroll
        for (int t = 0; t < 2; ++t) {
            const int buf = (2 * i + t) & 3;
            const unsigned short* bufA = &sA[buf][0];
            const unsigned short* bufB = &sB[buf][0];
            bf16x8 af[4], bfr[4];
#pragma unroll
            for (int mi = 0; mi < 4; mi++)
                af[mi] = *(const bf16x8*)(bufA + (mw + mi * 16 + l15) * 32
                                          + (quad ^ rslot) * 8);
#pragma unroll
            for (int ni = 0; ni < 4; ni++)
                bfr[ni] = *(const bf16x8*)(bufB + (nw + ni * 16 + l15) * 32
                                           + (quad ^ rslot) * 8);
#pragma unroll
            for (int mi = 0; mi < 4; mi++)
#pragma unroll
                for (int ni = 0; ni < 4; ni++)
                    acc[mi][ni] = __builtin_amdgcn_mfma_f32_16x16x32_bf16(
                        af[mi], bfr[ni], acc[mi][ni], 0, 0, 0);
        }

        // all waves done reading bufs {2i,2i+1}; refill them with {2i+4,2i+5}
        __builtin_amdgcn_s_barrier();
#pragma unroll
        for (int t = 0; t < 2; ++t) {
            const int kt = 2 * i + 4 + t;
            const int kpf = (kt * 32 <= kLast) ? kt * 32 : kLast;  // clamp tail
            const int buf = kt & 3;            // == (2i+t)&3, just freed
            unsigned short* dA = &sA[buf][0] + woff;
            unsigned short* dB = &sB[buf][0] + woff;
            gload16(pA + kpf,             dA);
            gload16(pA + kpf + rowskip16, dA + 512);
            gload16(pB + kpf,             dB);
            gload16(pB + kpf + rowskip16, dB + 512);
            MEMFENCE;
        }
    }
    asm volatile("s_waitcnt vmcnt(0)" ::: "memory");

    // epilogue: transposed fp32 store + bias + resid (line-contiguous in ns)
#pragma unroll
    for (int mi = 0; mi < 4; mi++) {
#pragma unroll
        for (int r = 0; r < 4; r++) {
            const int c = m0 + mw + mi * 16 + quad * 4 + r;
            const float bv = bias[c];
#pragma unroll
            for (int ni = 0; ni < 4; ni++) {
                const int j  = n0 + nw + ni * 16 + l15;
                const int bb = j >> 10, ns = j & 1023;
                const size_t a = (size_t)bb * CH * NSP + (size_t)c * NSP + ns;
                Of[a] = acc[mi][ni][r] + bv + resid[a];
            }
        }
    }
}

// ---------------------------------------------------------------------------
// r17: ffn1 as 8-PHASE 256x256 schedule (m194-m201 template, plain HIP).
// Hb = relu(O * W1^T + b1). BM=BN=256, BK=64, 512 threads = 8 waves (2m x
// 4n), wave tile 128x64, acc 8x4, 64 MFMA/K-tile/wave. LDS 128KB: 2-deep
// double buffer sA/sB[2][256][64]. K=512 -> 8 K-tiles x 4 phases of
// {ds_read subtile | stage half-tile(kt+1) | barrier | setprio(1) 16 MFMA
// setprio(0) | barrier}. Staging for kt+1 issued phases 0-1 (A then B),
// drained by ONE vmcnt(0) at end of phase 3 (~3 phases ~700cy cover > L2
// latency; O-stripe 2MB + W1 2MB L2-resident per XCD).
// st_16x32 swizzle (m201): physical_byte = logical ^ ((row&4)<<3), applied
// BOTH sides (rule #21): staging source chunk = (tid&7)^((tid&32)>>4),
// read chunk offset ^((l15&4)?16:0). Involution verified.
// r16 post-mortem: residency is not the lever (r14/r16 both null/negative);
// the 2-phase stage+vmcnt+barrier chain is structural (m233: 72%) -> only
// the 8-phase interleave (T3+T4, m196/m218: +28-73%) breaks it.
// ---------------------------------------------------------------------------
__global__ __launch_bounds__(512, 1)
void ffn1_8ph(const unsigned short* __restrict__ A,   // O  [16384][512]
              const unsigned short* __restrict__ Bm,  // W1 [2048][512]
              unsigned short* __restrict__ Cout,      // Hb [16384][2048]
              const float* __restrict__ bias)
{
    constexpr int K = CH;   // 512
    __shared__ unsigned short sA[2][256 * 64];   // 2 x 32 KB
    __shared__ unsigned short sB[2][256 * 64];   // 2 x 32 KB -> 128 KB

    const int tid  = threadIdx.x;
    const int lane = tid & 63;
    const int w    = tid >> 6;      // 0..7
    const int wr   = w >> 2;        // 0..1  (m half)
    const int wc   = w & 3;         // 0..3  (n quarter)
    const int quad = lane >> 4;
    const int l15  = lane & 15;
    const int swz  = (l15 & 4) ? 16 : 0;   // read-side st_16x32 (ushorts)

    const int F = blockIdx.x;       // 512 blocks
    const int xcd = F & 7, s = F >> 3;             // 8 m-tiles x 8 n / XCD
    const int m0 = ((xcd << 3) + (s >> 3)) << 8;
    const int n0 = (s & 7) << 8;

    // staging: 512 thr x 16B = 64 rows x 64 elems per pass; 4 passes/tile.
    // source chunk pre-swizzled so linear gload_lds dst yields st_16x32.
    const int srow   = tid >> 3;                       // 0..63
    const int schunk = (tid & 7) ^ ((tid & 32) >> 4);  // ^2 when row&4
    const unsigned short* pAg = A  + (size_t)(m0 + srow) * K + schunk * 8;
    const unsigned short* pBg = Bm + (size_t)(n0 + srow) * K + schunk * 8;
    const int dRow = w * 8;        // wave-uniform dst row base within pass

#define STAGE_A8(kt, nb) do {                                         \
    unsigned short* d = &sA[nb][0];                                   \
    const unsigned short* g = pAg + (kt) * 64;                        \
    gload16(g,                   d + (dRow      ) * 64);              \
    gload16(g + (size_t) 64 * K, d + (dRow +  64) * 64);              \
    gload16(g + (size_t)128 * K, d + (dRow + 128) * 64);              \
    gload16(g + (size_t)192 * K, d + (dRow + 192) * 64);              \
    MEMFENCE; } while (0)
#define STAGE_B8(kt, nb) do {                                         \
    unsigned short* d = &sB[nb][0];                                   \
    const unsigned short* g = pBg + (kt) * 64;                        \
    gload16(g,                   d + (dRow      ) * 64);              \
    gload16(g + (size_t) 64 * K, d + (dRow +  64) * 64);              \
    gload16(g + (size_t)128 * K, d + (dRow + 128) * 64);              \
    gload16(g + (size_t)192 * K, d + (dRow + 192) * 64);              \
    MEMFENCE; } while (0)

    floatx4 acc[8][4];
#pragma unroll
    for (int i = 0; i < 8; i++)
#pragma unroll
        for (int j = 0; j < 4; j++) acc[i][j] = (floatx4){0.f, 0.f, 0.f, 0.f};

    // prologue: K-tile 0 into buf 0
    STAGE_A8(0, 0);
    STAGE_B8(0, 0);
    asm volatile("s_waitcnt vmcnt(0)" ::: "memory");
    SBARRIER;

    bf16x8 af[4][2], bfr[4][2];

    for (int kt = 0; kt < 8; ++kt) {
        const unsigned short* bufA = &sA[kt & 1][0];
        const unsigned short* bufB = &sB[kt & 1][0];
        const int nb = (kt + 1) & 1;
        const bool pf = (kt < 7);

        // ---- phase 0: af(mi 0-3) + bfr(ni 0-1); stage A(kt+1)
#pragma unroll
        for (int i = 0; i < 4; i++) {
            const unsigned short* r = bufA + (size_t)(wr * 128 + i * 16 + l15) * 64;
            af[i][0] = *(const bf16x8*)(r + ((quad * 8) ^ swz));
            af[i][1] = *(const bf16x8*)(r + ((32 + quad * 8) ^ swz));
        }
#pragma unroll
        for (int j = 0; j < 2; j++) {
            const unsigned short* r = bufB + (size_t)(wc * 64 + j * 16 + l15) * 64;
            bfr[j][0] = *(const bf16x8*)(r + ((quad * 8) ^ swz));
            bfr[j][1] = *(const bf16x8*)(r + ((32 + quad * 8) ^ swz));
        }
        if (pf) STAGE_A8(kt + 1, nb);
        SBARRIER;
        __builtin_amdgcn_s_setprio(1);
#pragma unroll
        for (int i = 0; i < 4; i++)
#pragma unroll
            for (int j = 0; j < 2; j++)
#pragma unroll
                for (int kk = 0; kk < 2; kk++)
                    acc[i][j] = __builtin_amdgcn_mfma_f32_16x16x32_bf16(
                        af[i][kk], bfr[j][kk], acc[i][j], 0, 0, 0);
        __builtin_amdgcn_s_setprio(0);
        SBARRIER;

        // ---- phase 1: bfr(ni 2-3); stage B(kt+1)
#pragma unroll
        for (int j = 0; j < 2; j++) {
            const unsigned short* r = bufB + (size_t)(wc * 64 + (2 + j) * 16 + l15) * 64;
            bfr[2 + j][0] = *(const bf16x8*)(r + ((quad * 8) ^ swz));
            bfr[2 + j][1] = *(const bf16x8*)(r + ((32 + quad * 8) ^ swz));
        }
        if (pf) STAGE_B8(kt + 1, nb);
        SBARRIER;
        __builtin_amdgcn_s_setprio(1);
#pragma unroll
        for (int i = 0; i < 4; i++)
#pragma unroll
            for (int j = 0; j < 2; j++)
#pragma unroll
                for (int kk = 0; kk < 2; kk++)
                    acc[i][2 + j] = __builtin_amdgcn_mfma_f32_16x16x32_bf16(
                        af[i][kk], bfr[2 + j][kk], acc[i][2 + j], 0, 0, 0);
        __builtin_amdgcn_s_setprio(0);
        SBARRIER;

        // ---- phase 2: af(mi 4-7); MFMA vs bfr(ni 2-3)
#pragma unroll
        for (int i = 0; i < 4; i++) {
            const unsigned short* r = bufA + (size_t)(wr * 128 + 64 + i * 16 + l15) * 64;
            af[i][0] = *(const bf16x8*)(r + ((quad * 8) ^ swz));
            af[i][1] = *(const bf16x8*)(r + ((32 + quad * 8) ^ swz));
        }
        SBARRIER;
        __builtin_amdgcn_s_setprio(1);
#pragma unroll
        for (int i = 0; i < 4; i++)
#pragma unroll
            for (int j = 0; j < 2; j++)
#pragma unroll
                for (int kk = 0; kk < 2; kk++)
                    acc[4 + i][2 + j] = __builtin_amdgcn_mfma_f32_16x16x32_bf16(
                        af[i][kk], bfr[2 + j][kk], acc[4 + i][2 + j], 0, 0, 0);
        __builtin_amdgcn_s_setprio(0);
        SBARRIER;

        // ---- phase 3: MFMA af(mi 4-7) vs bfr(ni 0-1); drain stage, handoff
        __builtin_amdgcn_s_setprio(1);
#pragma unroll
        for (int i = 0; i < 4; i++)
#pragma unroll
            for (int j = 0; j < 2; j++)
#pragma unroll
                for (int kk = 0; kk < 2; kk++)
                    acc[4 + i][j] = __builtin_amdgcn_mfma_f32_16x16x32_bf16(
                        af[i][kk], bfr[j][kk], acc[4 + i][j], 0, 0, 0);
        __builtin_amdgcn_s_setprio(0);
        if (pf) {
            asm volatile("s_waitcnt vmcnt(0)" ::: "memory");
            SBARRIER;
        }
    }

    // epilogue: +bias, relu -> bf16; ni-inner (line-contiguous)
    float bv[4];
#pragma unroll
    for (int ni = 0; ni < 4; ni++)
        bv[ni] = bias[n0 + wc * 64 + ni * 16 + l15];
#pragma unroll
    for (int mi = 0; mi < 8; mi++) {
#pragma unroll
        for (int r = 0; r < 4; r++) {
            const size_t rowoff =
                (size_t)(m0 + wr * 128 + mi * 16 + quad * 4 + r) * HIDD;
#pragma unroll
            for (int ni = 0; ni < 4; ni++)
                Cout[rowoff + n0 + wc * 64 + ni * 16 + l15] =
                    f2bf(fmaxf(acc[mi][ni][r] + bv[ni], 0.f));
        }
    }
#undef STAGE_A8
#undef STAGE_B8
}

// merged prep: z<16 -> pack x (bf16 X + X^T); z>=16 -> cast w1,w2 to bf16
__global__ __launch_bounds__(256)
void prep_kernel(const float* __restrict__ x,
                 unsigned short* __restrict__ Xbf,
                 unsigned short* __restrict__ XT,
                 const float* __restrict__ w1,
                 unsigned short* __restrict__ W1b,
                 const float* __restrict__ w2,
                 unsigned short* __restrict__ W2b)
{
    const int tx = threadIdx.x, ty = threadIdx.y;
    const int z = blockIdx.z;
    if (z < 16) {
        __shared__ float tile[32][33];
        const int n0 = blockIdx.x * 32, c0 = blockIdx.y * 32, b = z;
        const size_t base = (size_t)b * CH * NSP;
#pragma unroll
        for (int i = ty; i < 32; i += 8) {
            float v = x[base + (size_t)(c0 + i) * NSP + n0 + tx];
            tile[i][tx] = v;
            Xbf[base + (size_t)(c0 + i) * NSP + n0 + tx] = f2bf(v);
        }
        __syncthreads();
        const size_t tbase = (size_t)b * NSP * CH;
#pragma unroll
        for (int i = ty; i < 32; i += 8)
            XT[tbase + (size_t)(n0 + i) * CH + c0 + tx] = f2bf(tile[tx][i]);
    } else {
        const int tid = ty * 32 + tx;
        const int blk = (z - 16) * 512 + blockIdx.y * 32 + blockIdx.x;
        const int i = blk * 256 + tid;                 // [0, 2*HIDD*CH)
        if (i < HIDD * CH) W1b[i] = f2bf(w1[i]);
        else               W2b[i - HIDD * CH] = f2bf(w2[i - HIDD * CH]);
    }
}

extern "C" void kernel_launch(void* const* d_in, const int* in_sizes, int n_in,
                              void* d_out, int out_size, void* d_ws, size_t ws_size,
                              hipStream_t stream)
{
    const float* x  = (const float*)d_in[0];
    const float* w1 = (const float*)d_in[1];
    const float* b1 = (const float*)d_in[2];
    const float* w2 = (const float*)d_in[3];
    const float* b2 = (const float*)d_in[4];
    float* out = (float*)d_out;

    char* ws = (char*)d_ws;
    unsigned short* Xbf = (unsigned short*)ws; ws += (size_t)BATCH * CH * NSP * 2;   // 16 MB
    unsigned short* XT  = (unsigned short*)ws; ws += (size_t)BATCH * NSP * CH * 2;   // 16 MB
    unsigned short* W1b = (unsigned short*)ws; ws += (size_t)HIDD * CH * 2;          //  2 MB
    unsigned short* W2b = (unsigned short*)ws; ws += (size_t)CH * HIDD * 2;          //  2 MB
    unsigned short* P   = (unsigned short*)ws; ws += (size_t)BATCH * NSP * NSP * 2;  // 32 MB
    unsigned short* O   = (unsigned short*)ws; ws += (size_t)BATCH * NSP * CH * 2;   // 16 MB
    unsigned short* Hb  = (unsigned short*)ws; ws += (size_t)BATCH * NSP * HIDD * 2; // 64 MB
    float*          Ps  = (float*)ws;          ws += (size_t)BATCH * NSP * 16 * 4;   //  1 MB

    const dim3 blk(256);

    // pack x (X, X^T) + cast weights, one launch
    prep_kernel<<<dim3(32, 16, 32), dim3(32, 8), 0, stream>>>(
        x, Xbf, XT, w1, W1b, w2, W2b);

    // expP = exp(scale * XT * XT^T) -> P (bf16) + chunk sums -> Ps
    // triangular: 36 tiles/batch, off-diag mirrored in epilogue
    gemm_bt<5, 4, 2><<<dim3(576), blk, 0, stream>>>(
        XT, XT, P, NSP, CH,
        (long)NSP * CH, (long)NSP * CH, (long)NSP * NSP, nullptr,
        0.04419417382415922f, nullptr, Ps);

    // O = (expP * X^T) * (1/rowsum)  — rowsum folded into PV prologue
    gemm_bt<6, 1, 2><<<dim3(512), blk, 0, stream>>>(
        P, Xbf, O, CH, NSP,
        (long)NSP * NSP, (long)CH * NSP, (long)NSP * CH, nullptr, 1.f,
        nullptr, Ps);

    // H = relu(O * W1^T + b1)  — r17: 8-phase 256x256, 512 threads
    ffn1_8ph<<<dim3(512), dim3(512), 0, stream>>>(O, W1b, Hb, b1);

    // out = (W2 * H^T)[c][b*n] + b2[c] + x  — r15: 2-K-tiles-per-body loop
    gemm_final_u2<<<dim3(512), blk, 0, stream>>>(
        W2b, Hb, out, b2, x);
}

// Round 6
// 233.433 us; speedup vs baseline: 1.1249x; 1.0168x over previous
//
#include <hip/hip_runtime.h>

#define BATCH 16
#define CH    512
#define NSP   1024
#define HIDD  2048

typedef __bf16 bf16x8 __attribute__((ext_vector_type(8)));
typedef float floatx4 __attribute__((ext_vector_type(4)));

__device__ __forceinline__ float bf2f(unsigned short u) {
    union { unsigned int i; float f; } v; v.i = ((unsigned int)u) << 16; return v.f;
}
__device__ __forceinline__ unsigned short f2bf(float f) {
    union { float f; unsigned int i; } v; v.f = f;
    unsigned int i = v.i;
    return (unsigned short)((i + 0x7FFFu + ((i >> 16) & 1u)) >> 16);
}

// async global->LDS, 16B per lane; LDS dst is wave-uniform base + lane*16
__device__ __forceinline__ void gload16(const void* g, void* l) {
    __builtin_amdgcn_global_load_lds(
        (__attribute__((address_space(1))) unsigned int*)(g),
        (__attribute__((address_space(3))) unsigned int*)(l),
        16, 0, 0);
}
#define MEMFENCE asm volatile("" ::: "memory")
#define SBARRIER asm volatile("s_barrier" ::: "memory")

// ---------------------------------------------------------------------------
// C = A (MxK, rm) * B^T (Bm NxK rm). 128x128 tile, BK=32, 4 waves,
// 4x4 mfma 16x16x32. r7-verified fine-vmcnt K-loop: DEPTH+1 LDS buffers,
// distance-DEPTH prefetch, 4 gload16/wave/iter, loop barrier =
//   s_waitcnt vmcnt(4*(DEPTH-1)); s_barrier
//
// MAP: 1 PV: XCD owns 2 batches (8x4 tiles);
//      4 scores: TRIANGULAR (S symmetric), 576 blocks, mirrored epilogue.
// EPI: 5 expP (no-max exp) + chunk sums, MAP4 mirror;
//      6 PV: multiply by 1/rowsum computed in-kernel from aux=Ps.
// Stores ni-inner (line-contiguous) -- r10 verified zero WRITE inflation.
// ---------------------------------------------------------------------------
template<int EPI, int MAP, int DEPTH>
__global__ __launch_bounds__(256, (DEPTH == 2) ? 3 : 2)
void gemm_bt(const unsigned short* __restrict__ A,
             const unsigned short* __restrict__ Bm,
             void* __restrict__ Cout,
             int Nn, int K,
             long sAb, long sBb, long sCb,
             const float* __restrict__ bias, float scale,
             const float* __restrict__ resid,
             float* __restrict__ aux)
{
    constexpr int NBUF = DEPTH + 1;
    __shared__ unsigned short sA[NBUF][128 * 32];
    __shared__ unsigned short sB[NBUF][128 * 32];
    __shared__ float sInv[128];

    const int tid  = threadIdx.x;
    const int lane = tid & 63;
    const int w    = tid >> 6;
    const int quad = lane >> 4;
    const int l15  = lane & 15;
    const int mw   = (w >> 1) * 64;
    const int nw   = (w & 1) * 64;

    const int F = blockIdx.x;
    int m0, n0, b;
    if constexpr (MAP == 1) {        // 512 blocks: 2 batches/XCD, 8x4 tiles
        const int xcd = F & 7, s = F >> 3;
        b = xcd + ((s >> 5) << 3);
        const int j = s & 31; m0 = (j >> 2) << 7; n0 = (j & 3) << 7;
    } else if constexpr (MAP == 3) { // 512 blocks: 16 n-tiles/XCD x 4 m
        const int xcd = F & 7, s = F >> 3;
        b = 0; m0 = (s & 3) << 7; n0 = ((xcd << 4) + (s >> 2)) << 7;
    } else {                         // MAP 4: 576 blocks, triangular scores
        const int xcd = F & 7; int s = F >> 3;   // s in [0,72)
        b = xcd + ((s >= 36) ? 8 : 0);
        if (s >= 36) s -= 36;
        int tm = 0;
        while (s >= 8 - tm) { s -= 8 - tm; tm++; }
        m0 = tm << 7; n0 = (tm + s) << 7;
    }

    // PV: compute 1/rowsum for this block's 128 rows (before staging!)
    if constexpr (EPI == 6) {
        if (tid < 128) {
            const float* p = aux + (size_t)b * NSP * 16
                           + (size_t)(m0 + tid) * 16;
            float s = 0.f;
#pragma unroll
            for (int k = 0; k < 16; k++) s += p[k];
            sInv[tid] = 1.0f / s;
        }
        MEMFENCE;
    }

    A  += (size_t)b * sAb;
    Bm += (size_t)b * sBb;

    const int srow = lane >> 2;
    const int sg   = (lane & 3) ^ ((lane >> 3) & 3);
    const unsigned short* pA = A  + (size_t)(m0 + w * 32 + srow) * K + sg * 8;
    const unsigned short* pB = Bm + (size_t)(n0 + w * 32 + srow) * K + sg * 8;
    const size_t rowskip16 = (size_t)16 * K;
    const int woff = w * 1024;
    const int rslot = ((l15 >> 1) & 3);

    floatx4 acc[4][4];
#pragma unroll
    for (int i = 0; i < 4; i++)
#pragma unroll
        for (int j = 0; j < 4; j++) acc[i][j] = (floatx4){0.f, 0.f, 0.f, 0.f};

    const int nIter = K >> 5;
    const int kLast = K - 32;

#pragma unroll
    for (int d = 0; d < DEPTH; ++d) {
        unsigned short* dA = &sA[d][0] + woff;
        unsigned short* dB = &sB[d][0] + woff;
        gload16(pA + d * 32,             dA);
        gload16(pA + d * 32 + rowskip16, dA + 512);
        gload16(pB + d * 32,             dB);
        gload16(pB + d * 32 + rowskip16, dB + 512);
        MEMFENCE;
    }

    int bcur = 0, bpf = DEPTH;
    for (int it = 0; it < nIter; ++it) {
        if constexpr (DEPTH == 2)
            asm volatile("s_waitcnt vmcnt(4)\n\ts_barrier" ::: "memory");
        else
            asm volatile("s_waitcnt vmcnt(8)\n\ts_barrier" ::: "memory");

        const int kpf = (it + DEPTH) * 32 <= kLast ? (it + DEPTH) * 32 : kLast;
        unsigned short* dA = &sA[0][0] + bpf * 4096 + woff;
        unsigned short* dB = &sB[0][0] + bpf * 4096 + woff;
        gload16(pA + kpf,             dA);
        gload16(pA + kpf + rowskip16, dA + 512);
        gload16(pB + kpf,             dB);
        gload16(pB + kpf + rowskip16, dB + 512);
        MEMFENCE;

        const unsigned short* bufA = &sA[0][0] + bcur * 4096;
        const unsigned short* bufB = &sB[0][0] + bcur * 4096;
        bf16x8 af[4], bfr[4];
#pragma unroll
        for (int mi = 0; mi < 4; mi++)
            af[mi] = *(const bf16x8*)(bufA + (mw + mi * 16 + l15) * 32
                                      + (quad ^ rslot) * 8);
#pragma unroll
        for (int ni = 0; ni < 4; ni++)
            bfr[ni] = *(const bf16x8*)(bufB + (nw + ni * 16 + l15) * 32
                                       + (quad ^ rslot) * 8);
#pragma unroll
        for (int mi = 0; mi < 4; mi++)
#pragma unroll
            for (int ni = 0; ni < 4; ni++)
                acc[mi][ni] = __builtin_amdgcn_mfma_f32_16x16x32_bf16(
                    af[mi], bfr[ni], acc[mi][ni], 0, 0, 0);

        bcur = bcur == NBUF - 1 ? 0 : bcur + 1;
        bpf  = bpf  == NBUF - 1 ? 0 : bpf  + 1;
    }
    asm volatile("s_waitcnt vmcnt(0)" ::: "memory");

    // epilogues: D row = quad*4 + reg, col = lane&15  (m89/m91-verified)
    if constexpr (EPI == 4) {
        float* Of = (float*)Cout;
#pragma unroll
        for (int mi = 0; mi < 4; mi++) {
#pragma unroll
            for (int r = 0; r < 4; r++) {
                const int c = m0 + mw + mi * 16 + quad * 4 + r;
                const float bv = bias[c];
#pragma unroll
                for (int ni = 0; ni < 4; ni++) {
                    const int j  = n0 + nw + ni * 16 + l15;
                    const int bb = j >> 10, ns = j & 1023;
                    const size_t a = (size_t)bb * CH * NSP + (size_t)c * NSP + ns;
                    Of[a] = acc[mi][ni][r] + bv + resid[a];
                }
            }
        }
    } else if constexpr (EPI == 5) {
#pragma unroll
        for (int mi = 0; mi < 4; mi++)
#pragma unroll
            for (int ni = 0; ni < 4; ni++)
#pragma unroll
                for (int r = 0; r < 4; r++)
                    acc[mi][ni][r] = __expf(acc[mi][ni][r] * scale);
        {
            const int chunk = (n0 + nw) >> 6;
            float* ps = aux + (size_t)b * NSP * 16;
#pragma unroll
            for (int mi = 0; mi < 4; mi++) {
#pragma unroll
                for (int r = 0; r < 4; r++) {
                    float s = acc[mi][0][r] + acc[mi][1][r]
                            + acc[mi][2][r] + acc[mi][3][r];
                    s += __shfl_xor(s, 1);
                    s += __shfl_xor(s, 2);
                    s += __shfl_xor(s, 4);
                    s += __shfl_xor(s, 8);
                    if (l15 == 0)
                        ps[(size_t)(m0 + mw + mi * 16 + quad * 4 + r) * 16
                           + chunk] = s;
                }
            }
        }
        unsigned short* Cb = (unsigned short*)Cout + (size_t)b * sCb;
#pragma unroll
        for (int mi = 0; mi < 4; mi++) {
#pragma unroll
            for (int r = 0; r < 4; r++) {
                const size_t rowoff =
                    (size_t)(m0 + mw + mi * 16 + quad * 4 + r) * Nn;
#pragma unroll
                for (int ni = 0; ni < 4; ni++)
                    Cb[rowoff + n0 + nw + ni * 16 + l15] =
                        f2bf(acc[mi][ni][r]);
            }
        }
        if constexpr (MAP == 4) {
            if (m0 != n0) {
                const int chunkt = (m0 + mw) >> 6;
                float* ps = aux + (size_t)b * NSP * 16;
#pragma unroll
                for (int ni = 0; ni < 4; ni++) {
                    float s = 0.f;
#pragma unroll
                    for (int mi = 0; mi < 4; mi++)
#pragma unroll
                        for (int r = 0; r < 4; r++) s += acc[mi][ni][r];
                    s += __shfl_xor(s, 16);
                    s += __shfl_xor(s, 32);
                    if (quad == 0)
                        ps[(size_t)(n0 + nw + ni * 16 + l15) * 16 + chunkt] = s;
                }
#pragma unroll
                for (int ni = 0; ni < 4; ni++) {
                    const size_t rowoff =
                        (size_t)(n0 + nw + ni * 16 + l15) * Nn;
#pragma unroll
                    for (int mi = 0; mi < 4; mi++) {
                        ushort4 v;
                        v.x = f2bf(acc[mi][ni][0]);
                        v.y = f2bf(acc[mi][ni][1]);
                        v.z = f2bf(acc[mi][ni][2]);
                        v.w = f2bf(acc[mi][ni][3]);
                        *(ushort4*)(Cb + rowoff + m0 + mw + mi * 16 + quad * 4)
                            = v;
                    }
                }
            }
        }
    } else {  // EPI == 6: PV, multiply by sInv[row]
        __syncthreads();   // publish sInv ds_writes to all waves
        unsigned short* Cb = (unsigned short*)Cout + (size_t)b * sCb;
#pragma unroll
        for (int mi = 0; mi < 4; mi++) {
#pragma unroll
            for (int r = 0; r < 4; r++) {
                const int lrow = mw + mi * 16 + quad * 4 + r;
                const float iv = sInv[lrow];
                const size_t rowoff = (size_t)(m0 + lrow) * Nn;
#pragma unroll
                for (int ni = 0; ni < 4; ni++)
                    Cb[rowoff + n0 + nw + ni * 16 + l15] =
                        f2bf(acc[mi][ni][r] * iv);
            }
        }
    }
}

// ---------------------------------------------------------------------------
// r15: final GEMM out = (W2 * H^T)^T-store + b2 + x, 128x128 tile,
// 2-K-TILES-PER-BODY loop. 4 bufs BK=32, one vmcnt(8) wait per 2 tiles,
// mid-barrier refill of just-freed buffers. ~1kcy/sync-round cost model
// calibrated by r15's win (65.5 -> <64, total -14us).
// MAP: XCD owns 16 n-tiles x 4 m (r13's MAP3).
// ---------------------------------------------------------------------------
__global__ __launch_bounds__(256, 2)
void gemm_final_u2(const unsigned short* __restrict__ A,   // W2b [512][2048]
                   const unsigned short* __restrict__ Bm,  // Hb [16384][2048]
                   float* __restrict__ Of,                 // out fp32
                   const float* __restrict__ bias,         // b2 [512]
                   const float* __restrict__ resid)        // x  fp32
{
    const int K = HIDD;                        // 2048, 64 K-tiles, 32 bodies
    __shared__ unsigned short sA[4][128 * 32]; // 4 x 8 KB
    __shared__ unsigned short sB[4][128 * 32]; // 4 x 8 KB  -> 64 KB total

    const int tid  = threadIdx.x;
    const int lane = tid & 63;
    const int w    = tid >> 6;
    const int quad = lane >> 4;
    const int l15  = lane & 15;
    const int mw   = (w >> 1) * 64;
    const int nw   = (w & 1) * 64;

    const int F = blockIdx.x;              // 512 blocks
    const int xcd = F & 7, s = F >> 3;     // MAP3: 16 n-tiles/XCD x 4 m
    const int m0 = (s & 3) << 7;
    const int n0 = ((xcd << 4) + (s >> 2)) << 7;

    const int srow = lane >> 2;
    const int sg   = (lane & 3) ^ ((lane >> 3) & 3);
    const unsigned short* pA = A  + (size_t)(m0 + w * 32 + srow) * K + sg * 8;
    const unsigned short* pB = Bm + (size_t)(n0 + w * 32 + srow) * K + sg * 8;
    const size_t rowskip16 = (size_t)16 * K;
    const int woff = w * 1024;
    const int rslot = ((l15 >> 1) & 3);

    floatx4 acc[4][4];
#pragma unroll
    for (int i = 0; i < 4; i++)
#pragma unroll
        for (int j = 0; j < 4; j++) acc[i][j] = (floatx4){0.f, 0.f, 0.f, 0.f};

    const int kLast = K - 32;

    // prologue: stage K-tiles 0..3 into bufs 0..3 (16 loads/wave)
#pragma unroll
    for (int d = 0; d < 4; ++d) {
        unsigned short* dA = &sA[d][0] + woff;
        unsigned short* dB = &sB[d][0] + woff;
        gload16(pA + d * 32,             dA);
        gload16(pA + d * 32 + rowskip16, dA + 512);
        gload16(pB + d * 32,             dB);
        gload16(pB + d * 32 + rowskip16, dB + 512);
        MEMFENCE;
    }

    const int nBody = K >> 6;   // 32 bodies, 2 K-tiles each
    for (int i = 0; i < nBody; ++i) {
        // retire the 8 loads of K-tiles {2i, 2i+1}; keep {2i+2,2i+3} in flight
        asm volatile("s_waitcnt vmcnt(8)\n\ts_barrier" ::: "memory");

#pragma unroll
        for (int t = 0; t < 2; ++t) {
            const int buf = (2 * i + t) & 3;
            const unsigned short* bufA = &sA[buf][0];
            const unsigned short* bufB = &sB[buf][0];
            bf16x8 af[4], bfr[4];
#pragma unroll
            for (int mi = 0; mi < 4; mi++)
                af[mi] = *(const bf16x8*)(bufA + (mw + mi * 16 + l15) * 32
                                          + (quad ^ rslot) * 8);
#pragma unroll
            for (int ni = 0; ni < 4; ni++)
                bfr[ni] = *(const bf16x8*)(bufB + (nw + ni * 16 + l15) * 32
                                           + (quad ^ rslot) * 8);
#pragma unroll
            for (int mi = 0; mi < 4; mi++)
#pragma unroll
                for (int ni = 0; ni < 4; ni++)
                    acc[mi][ni] = __builtin_amdgcn_mfma_f32_16x16x32_bf16(
                        af[mi], bfr[ni], acc[mi][ni], 0, 0, 0);
        }

        // all waves done reading bufs {2i,2i+1}; refill them with {2i+4,2i+5}
        __builtin_amdgcn_s_barrier();
#pragma unroll
        for (int t = 0; t < 2; ++t) {
            const int kt = 2 * i + 4 + t;
            const int kpf = (kt * 32 <= kLast) ? kt * 32 : kLast;  // clamp tail
            const int buf = kt & 3;            // == (2i+t)&3, just freed
            unsigned short* dA = &sA[buf][0] + woff;
            unsigned short* dB = &sB[buf][0] + woff;
            gload16(pA + kpf,             dA);
            gload16(pA + kpf + rowskip16, dA + 512);
            gload16(pB + kpf,             dB);
            gload16(pB + kpf + rowskip16, dB + 512);
            MEMFENCE;
        }
    }
    asm volatile("s_waitcnt vmcnt(0)" ::: "memory");

    // epilogue: transposed fp32 store + bias + resid (line-contiguous in ns)
#pragma unroll
    for (int mi = 0; mi < 4; mi++) {
#pragma unroll
        for (int r = 0; r < 4; r++) {
            const int c = m0 + mw + mi * 16 + quad * 4 + r;
            const float bv = bias[c];
#pragma unroll
            for (int ni = 0; ni < 4; ni++) {
                const int j  = n0 + nw + ni * 16 + l15;
                const int bb = j >> 10, ns = j & 1023;
                const size_t a = (size_t)bb * CH * NSP + (size_t)c * NSP + ns;
                Of[a] = acc[mi][ni][r] + bv + resid[a];
            }
        }
    }
}

// ---------------------------------------------------------------------------
// r17: ffn1 as 8-PHASE 256x256 schedule (m194-m201 template, plain HIP).
// r18 (this round): FULL 3-bit st-swizzle. r17 shipped with a 1-bit XOR
// (chunk ^= 2 when row&4) -> each ds_read_b128 hit only banks 0-15 or
// 16-31 (16 dwords/bank vs 8 min) -> SQ_LDS_BANK_CONFLICT 3.15M/dispatch
// = 12.3kcy/CU = ~20% of wall. Fix: physical chunk = logical ^ (row&7);
// all reads have row&7 = l15&7, so lanes 0-15 spread across all 8 chunks
// = all 32 banks = conflict-free. Staging source chunk (rule #21 involution):
// schunk = (tid&7) ^ ((tid>>3)&7); holds for all 4 row-offsets (64k, k<4,
// = 0 mod 8). Everything else identical to r17.
// ---------------------------------------------------------------------------
__global__ __launch_bounds__(512, 1)
void ffn1_8ph(const unsigned short* __restrict__ A,   // O  [16384][512]
              const unsigned short* __restrict__ Bm,  // W1 [2048][512]
              unsigned short* __restrict__ Cout,      // Hb [16384][2048]
              const float* __restrict__ bias)
{
    constexpr int K = CH;   // 512
    __shared__ unsigned short sA[2][256 * 64];   // 2 x 32 KB
    __shared__ unsigned short sB[2][256 * 64];   // 2 x 32 KB -> 128 KB

    const int tid  = threadIdx.x;
    const int lane = tid & 63;
    const int w    = tid >> 6;      // 0..7
    const int wr   = w >> 2;        // 0..1  (m half)
    const int wc   = w & 3;         // 0..3  (n quarter)
    const int quad = lane >> 4;
    const int l15  = lane & 15;
    const int swz8 = (l15 & 7) * 8;   // 3-bit read-side swizzle (ushorts)

    const int F = blockIdx.x;       // 512 blocks
    const int xcd = F & 7, s = F >> 3;             // 8 m-tiles x 8 n / XCD
    const int m0 = ((xcd << 3) + (s >> 3)) << 8;
    const int n0 = (s & 7) << 8;

    // staging: 512 thr x 16B = 64 rows x 64 elems per pass; 4 passes/tile.
    // source chunk pre-swizzled so linear gload_lds dst yields the 3-bit
    // st-swizzle: physical chunk (tid&7) holds logical (tid&7)^(row&7).
    const int srow   = tid >> 3;                       // 0..63
    const int schunk = (tid & 7) ^ ((tid >> 3) & 7);
    const unsigned short* pAg = A  + (size_t)(m0 + srow) * K + schunk * 8;
    const unsigned short* pBg = Bm + (size_t)(n0 + srow) * K + schunk * 8;
    const int dRow = w * 8;        // wave-uniform dst row base within pass

#define STAGE_A8(kt, nb) do {                                         \
    unsigned short* d = &sA[nb][0];                                   \
    const unsigned short* g = pAg + (kt) * 64;                        \
    gload16(g,                   d + (dRow      ) * 64);              \
    gload16(g + (size_t) 64 * K, d + (dRow +  64) * 64);              \
    gload16(g + (size_t)128 * K, d + (dRow + 128) * 64);              \
    gload16(g + (size_t)192 * K, d + (dRow + 192) * 64);              \
    MEMFENCE; } while (0)
#define STAGE_B8(kt, nb) do {                                         \
    unsigned short* d = &sB[nb][0];                                   \
    const unsigned short* g = pBg + (kt) * 64;                        \
    gload16(g,                   d + (dRow      ) * 64);              \
    gload16(g + (size_t) 64 * K, d + (dRow +  64) * 64);              \
    gload16(g + (size_t)128 * K, d + (dRow + 128) * 64);              \
    gload16(g + (size_t)192 * K, d + (dRow + 192) * 64);              \
    MEMFENCE; } while (0)

    floatx4 acc[8][4];
#pragma unroll
    for (int i = 0; i < 8; i++)
#pragma unroll
        for (int j = 0; j < 4; j++) acc[i][j] = (floatx4){0.f, 0.f, 0.f, 0.f};

    // prologue: K-tile 0 into buf 0
    STAGE_A8(0, 0);
    STAGE_B8(0, 0);
    asm volatile("s_waitcnt vmcnt(0)" ::: "memory");
    SBARRIER;

    bf16x8 af[4][2], bfr[4][2];

    for (int kt = 0; kt < 8; ++kt) {
        const unsigned short* bufA = &sA[kt & 1][0];
        const unsigned short* bufB = &sB[kt & 1][0];
        const int nb = (kt + 1) & 1;
        const bool pf = (kt < 7);

        // ---- phase 0: af(mi 0-3) + bfr(ni 0-1); stage A(kt+1)
#pragma unroll
        for (int i = 0; i < 4; i++) {
            const unsigned short* r = bufA + (size_t)(wr * 128 + i * 16 + l15) * 64;
            af[i][0] = *(const bf16x8*)(r + ((quad * 8) ^ swz8));
            af[i][1] = *(const bf16x8*)(r + ((32 + quad * 8) ^ swz8));
        }
#pragma unroll
        for (int j = 0; j < 2; j++) {
            const unsigned short* r = bufB + (size_t)(wc * 64 + j * 16 + l15) * 64;
            bfr[j][0] = *(const bf16x8*)(r + ((quad * 8) ^ swz8));
            bfr[j][1] = *(const bf16x8*)(r + ((32 + quad * 8) ^ swz8));
        }
        if (pf) STAGE_A8(kt + 1, nb);
        SBARRIER;
        __builtin_amdgcn_s_setprio(1);
#pragma unroll
        for (int i = 0; i < 4; i++)
#pragma unroll
            for (int j = 0; j < 2; j++)
#pragma unroll
                for (int kk = 0; kk < 2; kk++)
                    acc[i][j] = __builtin_amdgcn_mfma_f32_16x16x32_bf16(
                        af[i][kk], bfr[j][kk], acc[i][j], 0, 0, 0);
        __builtin_amdgcn_s_setprio(0);
        SBARRIER;

        // ---- phase 1: bfr(ni 2-3); stage B(kt+1)
#pragma unroll
        for (int j = 0; j < 2; j++) {
            const unsigned short* r = bufB + (size_t)(wc * 64 + (2 + j) * 16 + l15) * 64;
            bfr[2 + j][0] = *(const bf16x8*)(r + ((quad * 8) ^ swz8));
            bfr[2 + j][1] = *(const bf16x8*)(r + ((32 + quad * 8) ^ swz8));
        }
        if (pf) STAGE_B8(kt + 1, nb);
        SBARRIER;
        __builtin_amdgcn_s_setprio(1);
#pragma unroll
        for (int i = 0; i < 4; i++)
#pragma unroll
            for (int j = 0; j < 2; j++)
#pragma unroll
                for (int kk = 0; kk < 2; kk++)
                    acc[i][2 + j] = __builtin_amdgcn_mfma_f32_16x16x32_bf16(
                        af[i][kk], bfr[2 + j][kk], acc[i][2 + j], 0, 0, 0);
        __builtin_amdgcn_s_setprio(0);
        SBARRIER;

        // ---- phase 2: af(mi 4-7); MFMA vs bfr(ni 2-3)
#pragma unroll
        for (int i = 0; i < 4; i++) {
            const unsigned short* r = bufA + (size_t)(wr * 128 + 64 + i * 16 + l15) * 64;
            af[i][0] = *(const bf16x8*)(r + ((quad * 8) ^ swz8));
            af[i][1] = *(const bf16x8*)(r + ((32 + quad * 8) ^ swz8));
        }
        SBARRIER;
        __builtin_amdgcn_s_setprio(1);
#pragma unroll
        for (int i = 0; i < 4; i++)
#pragma unroll
            for (int j = 0; j < 2; j++)
#pragma unroll
                for (int kk = 0; kk < 2; kk++)
                    acc[4 + i][2 + j] = __builtin_amdgcn_mfma_f32_16x16x32_bf16(
                        af[i][kk], bfr[2 + j][kk], acc[4 + i][2 + j], 0, 0, 0);
        __builtin_amdgcn_s_setprio(0);
        SBARRIER;

        // ---- phase 3: MFMA af(mi 4-7) vs bfr(ni 0-1); drain stage, handoff
        __builtin_amdgcn_s_setprio(1);
#pragma unroll
        for (int i = 0; i < 4; i++)
#pragma unroll
            for (int j = 0; j < 2; j++)
#pragma unroll
                for (int kk = 0; kk < 2; kk++)
                    acc[4 + i][j] = __builtin_amdgcn_mfma_f32_16x16x32_bf16(
                        af[i][kk], bfr[j][kk], acc[4 + i][j], 0, 0, 0);
        __builtin_amdgcn_s_setprio(0);
        if (pf) {
            asm volatile("s_waitcnt vmcnt(0)" ::: "memory");
            SBARRIER;
        }
    }

    // epilogue: +bias, relu -> bf16; ni-inner (line-contiguous)
    float bv[4];
#pragma unroll
    for (int ni = 0; ni < 4; ni++)
        bv[ni] = bias[n0 + wc * 64 + ni * 16 + l15];
#pragma unroll
    for (int mi = 0; mi < 8; mi++) {
#pragma unroll
        for (int r = 0; r < 4; r++) {
            const size_t rowoff =
                (size_t)(m0 + wr * 128 + mi * 16 + quad * 4 + r) * HIDD;
#pragma unroll
            for (int ni = 0; ni < 4; ni++)
                Cout[rowoff + n0 + wc * 64 + ni * 16 + l15] =
                    f2bf(fmaxf(acc[mi][ni][r] + bv[ni], 0.f));
        }
    }
#undef STAGE_A8
#undef STAGE_B8
}

// merged prep: z<16 -> pack x (bf16 X + X^T); z>=16 -> cast w1,w2 to bf16
__global__ __launch_bounds__(256)
void prep_kernel(const float* __restrict__ x,
                 unsigned short* __restrict__ Xbf,
                 unsigned short* __restrict__ XT,
                 const float* __restrict__ w1,
                 unsigned short* __restrict__ W1b,
                 const float* __restrict__ w2,
                 unsigned short* __restrict__ W2b)
{
    const int tx = threadIdx.x, ty = threadIdx.y;
    const int z = blockIdx.z;
    if (z < 16) {
        __shared__ float tile[32][33];
        const int n0 = blockIdx.x * 32, c0 = blockIdx.y * 32, b = z;
        const size_t base = (size_t)b * CH * NSP;
#pragma unroll
        for (int i = ty; i < 32; i += 8) {
            float v = x[base + (size_t)(c0 + i) * NSP + n0 + tx];
            tile[i][tx] = v;
            Xbf[base + (size_t)(c0 + i) * NSP + n0 + tx] = f2bf(v);
        }
        __syncthreads();
        const size_t tbase = (size_t)b * NSP * CH;
#pragma unroll
        for (int i = ty; i < 32; i += 8)
            XT[tbase + (size_t)(n0 + i) * CH + c0 + tx] = f2bf(tile[tx][i]);
    } else {
        const int tid = ty * 32 + tx;
        const int blk = (z - 16) * 512 + blockIdx.y * 32 + blockIdx.x;
        const int i = blk * 256 + tid;                 // [0, 2*HIDD*CH)
        if (i < HIDD * CH) W1b[i] = f2bf(w1[i]);
        else               W2b[i - HIDD * CH] = f2bf(w2[i - HIDD * CH]);
    }
}

extern "C" void kernel_launch(void* const* d_in, const int* in_sizes, int n_in,
                              void* d_out, int out_size, void* d_ws, size_t ws_size,
                              hipStream_t stream)
{
    const float* x  = (const float*)d_in[0];
    const float* w1 = (const float*)d_in[1];
    const float* b1 = (const float*)d_in[2];
    const float* w2 = (const float*)d_in[3];
    const float* b2 = (const float*)d_in[4];
    float* out = (float*)d_out;

    char* ws = (char*)d_ws;
    unsigned short* Xbf = (unsigned short*)ws; ws += (size_t)BATCH * CH * NSP * 2;   // 16 MB
    unsigned short* XT  = (unsigned short*)ws; ws += (size_t)BATCH * NSP * CH * 2;   // 16 MB
    unsigned short* W1b = (unsigned short*)ws; ws += (size_t)HIDD * CH * 2;          //  2 MB
    unsigned short* W2b = (unsigned short*)ws; ws += (size_t)CH * HIDD * 2;          //  2 MB
    unsigned short* P   = (unsigned short*)ws; ws += (size_t)BATCH * NSP * NSP * 2;  // 32 MB
    unsigned short* O   = (unsigned short*)ws; ws += (size_t)BATCH * NSP * CH * 2;   // 16 MB
    unsigned short* Hb  = (unsigned short*)ws; ws += (size_t)BATCH * NSP * HIDD * 2; // 64 MB
    float*          Ps  = (float*)ws;          ws += (size_t)BATCH * NSP * 16 * 4;   //  1 MB

    const dim3 blk(256);

    // pack x (X, X^T) + cast weights, one launch
    prep_kernel<<<dim3(32, 16, 32), dim3(32, 8), 0, stream>>>(
        x, Xbf, XT, w1, W1b, w2, W2b);

    // expP = exp(scale * XT * XT^T) -> P (bf16) + chunk sums -> Ps
    // triangular: 36 tiles/batch, off-diag mirrored in epilogue
    gemm_bt<5, 4, 2><<<dim3(576), blk, 0, stream>>>(
        XT, XT, P, NSP, CH,
        (long)NSP * CH, (long)NSP * CH, (long)NSP * NSP, nullptr,
        0.04419417382415922f, nullptr, Ps);

    // O = (expP * X^T) * (1/rowsum)  — rowsum folded into PV prologue
    gemm_bt<6, 1, 2><<<dim3(512), blk, 0, stream>>>(
        P, Xbf, O, CH, NSP,
        (long)NSP * NSP, (long)CH * NSP, (long)NSP * CH, nullptr, 1.f,
        nullptr, Ps);

    // H = relu(O * W1^T + b1)  — r18: 8-phase 256x256 + full 3-bit swizzle
    ffn1_8ph<<<dim3(512), dim3(512), 0, stream>>>(O, W1b, Hb, b1);

    // out = (W2 * H^T)[c][b*n] + b2[c] + x  — r15: 2-K-tiles-per-body loop
    gemm_final_u2<<<dim3(512), blk, 0, stream>>>(
        W2b, Hb, out, b2, x);
}